// Round 3
// baseline (519.991 us; speedup 1.0000x reference)
//
#include <hip/hip_runtime.h>
#include <hip/hip_bf16.h>
#include <stdint.h>

// Mahalanobis loss via Gram reformulation:
//   mean_n (f_n-mu)^T C (f_n-mu)
//     = (1/N)[ <C, G> - sum_{d,e} C_de (coef_d mu_e + mu_d coef_e) ],
//   G = Fb^T Fb (bf16, fp32 accum), s = sum_n fb_n, coef = s - (N/2) mu.
//
// R6: R5 proved the limiter is the per-iteration serial staging structure
// (occupancy 2x -> only -8%; all pipes <30%): reg-staged fp32 loads + cvt +
// transpose + ds_writes + full-drain __syncthreads every 64-row chunk.
// This round restructures the dataflow:
//   1) maha_prep: one streaming pass F[n][d] f32 -> Ft[d][n] bf16 (LDS-tiled
//      transpose) + fused column-sums s (atomicAdd). ~400 MB => BW-floor pass.
//   2) maha_gram: both operands now [row][k]-contiguous => staging is pure
//      global_load_lds dwordx4 (no VGPR roundtrip, no cvt/transpose VALU).
//      Bank swizzle applied on the GLOBAL source per-lane address (LDS linear,
//      rule both-sides-or-neither): lane off = ((l&7)*16)^((l>>3)<<4), read
//      off = kb^((row&7)<<4)  -> enumerated 2 lanes/bank (free).
//      Raw s_barrier + counted s_waitcnt vmcnt(4) (2 diag): next-chunk loads
//      stay in flight across barriers (T3/T4-lite); lgkmcnt(0) before
//      barrier2 guards WAR on slot reuse. Waves: 2x2 spatial x 2-way K-split,
//      acc[4][4]; staging regs freed -> ~110 VGPR under (512,2)'s 128 cap.

typedef __attribute__((ext_vector_type(8))) short short8;
typedef __attribute__((ext_vector_type(4))) float floatx4;

static constexpr int NROWS = 131072;
static constexpr int DDIM  = 512;

__device__ __forceinline__ short f2bf(float f) {
  __bf16 b = (__bf16)f;                   // RNE f32->bf16
  return __builtin_bit_cast(short, b);
}
__device__ __forceinline__ float bf2f(short s) {
  __bf16 b = __builtin_bit_cast(__bf16, s);
  return (float)b;
}

__device__ __forceinline__ void gld16(const void* g, void* l) {
  __builtin_amdgcn_global_load_lds(
      (const __attribute__((address_space(1))) void*)g,
      (__attribute__((address_space(3))) void*)l, 16, 0, 0);
}

// ---- zero-init: s[512] and out (both poisoned 0xAA before every launch) ----
__global__ __launch_bounds__(512) void maha_zero(float* __restrict__ s_ws,
                                                 float* __restrict__ out) {
  s_ws[threadIdx.x] = 0.0f;
  if (threadIdx.x == 0) out[0] = 0.0f;
}

// ---- pre-pass: F[n][d] f32 -> Ft[d][n] bf16, fused s[d] = sum_n fb ----
// Tile: 256 n x 64 d per block. Grid 512 x 8 = 4096 blocks.
__global__ __launch_bounds__(256) void maha_prep(const float* __restrict__ F,
                                                 short* __restrict__ Ft,
                                                 float* __restrict__ s_ws) {
  // stride 280 shorts: 16B-aligned rows; phase-2 bank groups 12d mod 32 ->
  // 8 distinct non-overlapping 4-bank groups, 2 lanes/bank (free).
  __shared__ short T[64][280];
  const int bn = blockIdx.x & 511;        // n-stripe (256 rows)
  const int bd = blockIdx.x >> 9;         // d-window (64 cols)
  const int n0 = bn * 256, d0 = bd * 64;
  const int t = threadIdx.x;

  // phase 1: thread t reads row n0+t cols [d0,d0+64), cvt, scatter to T cols
  const float* rp = F + (size_t)(n0 + t) * DDIM + d0;
#pragma unroll
  for (int k = 0; k < 16; k++) {
    floatx4 v4 = *(const floatx4*)(rp + 4 * k);
#pragma unroll
    for (int j = 0; j < 4; j++) T[4 * k + j][t] = f2bf(v4[j]);
  }
  __syncthreads();

  // phase 2: thread (d = t>>2, part = t&3) streams T[d][64*part..+64) out
  const int d = t >> 2, part = t & 3;
  float s = 0.f;
  short* orow = Ft + (size_t)(d0 + d) * NROWS + n0 + 64 * part;
#pragma unroll
  for (int i = 0; i < 8; i++) {
    short8 w = *(const short8*)&T[d][64 * part + 8 * i];
    *(short8*)(orow + 8 * i) = w;
#pragma unroll
    for (int j = 0; j < 8; j++) s += bf2f(w[j]);
  }
  s += __shfl_down(s, 1);                 // reduce 4 consecutive lanes
  s += __shfl_down(s, 2);
  if (part == 0) atomicAdd(&s_ws[d0 + d], s);  // 512 adds per address total
}

// ---- main: symmetric Gram tiles from Ft, fused <C,G> epilogue ----
__global__ __launch_bounds__(512, 2) void maha_gram(const short* __restrict__ Ft,
                                                    const float* __restrict__ C,
                                                    float* __restrict__ out) {
  // A dbuf: ABs[0..16384) shorts, B dbuf: ABs[16384..32768). 64 KB total.
  // Slot = 128 rows x 64 k bf16, linear rows of 128 B; content XOR-swizzled
  // via the global source address (global_load_lds dest must be linear).
  __shared__ short ABs[32768];
  __shared__ float red[8];

  static const int TI[10] = {0,0,0,0,1,1,1,2,2,3};
  static const int TJ[10] = {0,1,2,3,1,2,3,2,3,3};

  const int bid  = blockIdx.x;
  const int gg   = bid / 80;
  const int rr   = bid % 80;
  const int slab = gg * 8 + (rr & 7);     // 0..127, 1024 K-rows each
  const int tile = rr >> 3;               // 0..9
  const int ti = TI[tile], tj = TJ[tile];
  const bool diag = (ti == tj);

  const int th = threadIdx.x;
  const int wave = th >> 6, lane = th & 63;

  // ---- staging: 16 gld16 per matrix per chunk (8 rows each); wave w owns
  // row-groups 8w and 64+8w. Global per-lane offset carries the inverse
  // swizzle so linear LDS holds the swizzled layout.
  const int lrow = lane >> 3;                       // row within 8-row group
  const int lno  = ((lane & 7) * 16) ^ (lrow << 4); // swizzled byte-in-row
  const char* FtB = (const char*)Ft;
  const size_t RSTRIDE = (size_t)NROWS * 2;         // bytes per Ft row
  const char* gA0 = FtB + (size_t)(128 * ti + 8 * wave + lrow) * RSTRIDE + lno;
  const char* gA1 = gA0 + (size_t)64 * RSTRIDE;
  const char* gB0 = FtB + (size_t)(128 * tj + 8 * wave + lrow) * RSTRIDE + lno;
  const char* gB1 = gB0 + (size_t)64 * RSTRIDE;
  short* lA0 = &ABs[(8 * wave) * 64];
  short* lA1 = &ABs[(64 + 8 * wave) * 64];
  short* lB0 = &ABs[16384 + (8 * wave) * 64];
  short* lB1 = &ABs[16384 + (64 + 8 * wave) * 64];

  auto issue = [&](int c) {               // 4 loads/wave (2 if diag)
    const int sb = (c & 1) * 8192;
    const size_t nb2 = ((size_t)slab * 1024 + (size_t)c * 64) * 2;
    gld16(gA0 + nb2, lA0 + sb);
    gld16(gA1 + nb2, lA1 + sb);
    if (!diag) {
      gld16(gB0 + nb2, lB0 + sb);
      gld16(gB1 + nb2, lB1 + sb);
    }
  };

  // ---- MFMA mapping: 2x2 spatial x 2-way K-split over the 128x128 tile ----
  const int wk = wave & 1;                // K-half of the 64-row chunk
  const int wm = (wave >> 1) & 1;
  const int wn = wave >> 2;
  const int l15 = lane & 15, quad = lane >> 4;
  const int kb = wk * 64 + quad * 16;     // byte offset of this lane's K-slice

  int idxA[4], idxB[4];                   // constant short-offsets (per slot)
#pragma unroll
  for (int mi = 0; mi < 4; mi++) {
    const int r = wm * 64 + mi * 16 + l15;
    idxA[mi] = r * 64 + ((kb ^ ((r & 7) << 4)) >> 1);
    const int e = wn * 64 + mi * 16 + l15;
    idxB[mi] = e * 64 + ((kb ^ ((e & 7) << 4)) >> 1);
  }
  const int bbase = diag ? 0 : 16384;     // diag reads B from the A buffer

  floatx4 acc[4][4];
#pragma unroll
  for (int i = 0; i < 4; i++)
#pragma unroll
    for (int j = 0; j < 4; j++) acc[i][j] = floatx4{0.f, 0.f, 0.f, 0.f};

  issue(0);
  issue(1);

#pragma unroll 2
  for (int c = 0; c < 16; ++c) {
    // counted wait: leave chunk c+1's loads in flight (drain only at c=15)
    if (c == 15)      asm volatile("s_waitcnt vmcnt(0)" ::: "memory");
    else if (diag)    asm volatile("s_waitcnt vmcnt(2)" ::: "memory");
    else              asm volatile("s_waitcnt vmcnt(4)" ::: "memory");
    __builtin_amdgcn_s_barrier();         // slot c fully staged for all waves
    const int sb = (c & 1) * 8192;
    short8 af[4];
#pragma unroll
    for (int mi = 0; mi < 4; mi++) af[mi] = *(const short8*)&ABs[sb + idxA[mi]];
#pragma unroll
    for (int fj = 0; fj < 4; fj++) {
      const short8 bf = *(const short8*)&ABs[bbase + sb + idxB[fj]];
#pragma unroll
      for (int mi = 0; mi < 4; mi++)
        acc[mi][fj] = __builtin_amdgcn_mfma_f32_16x16x32_bf16(
            af[mi], bf, acc[mi][fj], 0, 0, 0);
    }
    asm volatile("s_waitcnt lgkmcnt(0)" ::: "memory");  // WAR guard: my reads retired
    __builtin_amdgcn_s_barrier();         // all waves done reading slot c
    if (c < 14) issue(c + 2);             // overwrite slot c (safe past barrier2)
  }

  // ---- epilogue: psum = sum W_de * G_de, W = C_ij (+ C_ji^T if offdiag) ----
  // K-split partners (wk=0/1) hold partial G for the same (d,e) region; both
  // contract with the same C weights -> psum adds correctly across waves.
  const int d0 = ti * 128, e0 = tj * 128;
  float psum = 0.f;
#pragma unroll
  for (int mi = 0; mi < 4; mi++) {
#pragma unroll
    for (int fj = 0; fj < 4; fj++) {
      const int dg = d0 + wm * 64 + mi * 16 + quad * 4;
      const int eg = e0 + wn * 64 + fj * 16 + l15;
#pragma unroll
      for (int r2 = 0; r2 < 4; r2++) {
        float wgt = C[(size_t)(dg + r2) * DDIM + eg];
        if (!diag) wgt += C[(size_t)eg * DDIM + dg + r2];
        psum += wgt * acc[mi][fj][r2];
      }
    }
  }

#pragma unroll
  for (int off = 32; off > 0; off >>= 1) psum += __shfl_down(psum, off);
  if (lane == 0) red[wave] = psum;
  __syncthreads();
  if (th == 0) {
    const float tot = red[0] + red[1] + red[2] + red[3] +
                      red[4] + red[5] + red[6] + red[7];
    atomicAdd(out, tot * (1.0f / (float)NROWS));
  }
}

// ---- correction: out += -(1/N) sum_{d,e} C_de (coef_d mu_e + mu_d coef_e) ----
__global__ __launch_bounds__(256) void maha_corr(const float* __restrict__ C,
                                                 const float* __restrict__ mu,
                                                 const float* __restrict__ s_ws,
                                                 float* __restrict__ out) {
  __shared__ float red[4];
  const int b = blockIdx.x;               // 128 blocks x 4 d-rows
  const int th = threadIdx.x;
  float cd[4], md[4];
#pragma unroll
  for (int dd = 0; dd < 4; dd++) {
    const int d = b * 4 + dd;
    md[dd] = mu[d];
    cd[dd] = s_ws[d] - 0.5f * (float)NROWS * md[dd];
  }
  float p = 0.f;
#pragma unroll
  for (int rep = 0; rep < 2; rep++) {
    const int e = th + rep * 256;
    const float me = mu[e];
    const float ce = s_ws[e] - 0.5f * (float)NROWS * me;
#pragma unroll
    for (int dd = 0; dd < 4; dd++)
      p += C[(size_t)(b * 4 + dd) * DDIM + e] * (cd[dd] * me + md[dd] * ce);
  }
  const int lane = th & 63, wave = th >> 6;
#pragma unroll
  for (int off = 32; off > 0; off >>= 1) p += __shfl_down(p, off);
  if (lane == 0) red[wave] = p;
  __syncthreads();
  if (th == 0)
    atomicAdd(out, -(red[0] + red[1] + red[2] + red[3]) * (1.0f / (float)NROWS));
}

extern "C" void kernel_launch(void* const* d_in, const int* in_sizes, int n_in,
                              void* d_out, int out_size, void* d_ws, size_t ws_size,
                              hipStream_t stream) {
  const float* feature = (const float*)d_in[0];   // [131072, 512] fp32
  const float* mean    = (const float*)d_in[1];   // [512] fp32
  const float* invcov  = (const float*)d_in[2];   // [512, 512] fp32
  float* out = (float*)d_out;                     // scalar fp32
  float* s_ws = (float*)d_ws;                     // s[512] fp32
  short* Ft   = (short*)((char*)d_ws + 4096);     // [512][131072] bf16, 134 MB

  maha_zero<<<1, 512, 0, stream>>>(s_ws, out);
  maha_prep<<<4096, 256, 0, stream>>>(feature, Ft, s_ws);
  maha_gram<<<1280, 512, 0, stream>>>(Ft, invcov, out);
  maha_corr<<<128, 256, 0, stream>>>(invcov, mean, s_ws, out);
}